// Round 8
// baseline (277.092 us; speedup 1.0000x reference)
//
#include <hip/hip_runtime.h>
#include <hip/hip_bf16.h>

#define T_TOK 2048
#define DDIM  1024
#define HDIM  2048
#define NEXP  8
#define NSEG  9   // 8 routed + 1 shared

typedef unsigned short u16;
typedef __attribute__((ext_vector_type(4))) float f32x4;
typedef __attribute__((ext_vector_type(8))) short bf16x8;
typedef __attribute__((ext_vector_type(4))) unsigned short u16x4;

__device__ __forceinline__ u16 f2bf(float x) {
  union { float f; unsigned int u; } v; v.f = x;
  unsigned int r = v.u + 0x7fffu + ((v.u >> 16) & 1u);
  return (u16)(r >> 16);
}
__device__ __forceinline__ float gelu_exact(float x) {
  return 0.5f * x * (1.0f + erff(x * 0.70710678118654752f));
}
// chunk swizzle for 64B rows (4 x 16B chunks)
__device__ __forceinline__ int swz4(int row) {
  return (row & 3) ^ ((row >> 2) & 3);
}

__device__ __forceinline__ void gload16(const void* g, void* l) {
  __builtin_amdgcn_global_load_lds(
      (const __attribute__((address_space(1))) unsigned int*)g,
      (__attribute__((address_space(3))) unsigned int*)l, 16, 0, 0);
}

// ---------------- router: logits, softmax, top-2, lists, bf16 X ----------------
__global__ __launch_bounds__(256) void router_kernel(
    const float* __restrict__ x, const float* __restrict__ rw,
    const float* __restrict__ rb, u16* __restrict__ xb,
    float* __restrict__ weights, int* __restrict__ counts,
    int* __restrict__ lists)
{
  int wv = threadIdx.x >> 6, lane = threadIdx.x & 63;
  int t = blockIdx.x * 4 + wv;            // one wave per token
  const float* xrow = x + (size_t)t * DDIM;
  float acc[NEXP];
#pragma unroll
  for (int e = 0; e < NEXP; e++) acc[e] = 0.f;
#pragma unroll
  for (int i = 0; i < 4; i++) {
    int d0 = i * 256 + lane * 4;
    f32x4 xv = *(const f32x4*)(xrow + d0);
    u16x4 pk;
#pragma unroll
    for (int j = 0; j < 4; j++) {
      float xs = xv[j];
      pk[j] = f2bf(xs);
      const float* wr = rw + (size_t)(d0 + j) * NEXP;
#pragma unroll
      for (int e = 0; e < NEXP; e++) acc[e] = fmaf(xs, wr[e], acc[e]);
    }
    *(u16x4*)(xb + (size_t)t * DDIM + d0) = pk;
  }
#pragma unroll
  for (int off = 32; off >= 1; off >>= 1)
#pragma unroll
    for (int e = 0; e < NEXP; e++) acc[e] += __shfl_xor(acc[e], off);

  if (lane == 0) {
    float lg[NEXP], mx = -1e30f;
#pragma unroll
    for (int e = 0; e < NEXP; e++) { lg[e] = acc[e] + rb[e]; mx = fmaxf(mx, lg[e]); }
    float p[NEXP], s = 0.f;
#pragma unroll
    for (int e = 0; e < NEXP; e++) { p[e] = expf(lg[e] - mx); s += p[e]; }
    float inv = 1.0f / s;
#pragma unroll
    for (int e = 0; e < NEXP; e++) p[e] *= inv;
    int i1 = 0;
#pragma unroll
    for (int e = 1; e < NEXP; e++) if (p[e] > p[i1]) i1 = e;
    int i2 = (i1 == 0) ? 1 : 0;
#pragma unroll
    for (int e = 0; e < NEXP; e++) if (e != i1 && p[e] > p[i2]) i2 = e;
#pragma unroll
    for (int e = 0; e < NEXP; e++)
      weights[(size_t)t * NEXP + e] = (e == i1) ? p[i1] : (e == i2) ? p[i2] : 0.f;
    int p1 = atomicAdd(counts + i1, 1); lists[i1 * T_TOK + p1] = t;
    int p2 = atomicAdd(counts + i2, 1); lists[i2 * T_TOK + p2] = t;
    lists[NEXP * T_TOK + t] = t;        // shared segment: identity
  }
}

// seg offsets + compact y-tile table (e*256+my for non-empty 256-row tiles)
__global__ void seg_kernel(int* counts, int* segoff, int* ytab, int* nyt) {
  counts[NEXP] = T_TOK;
  int off = 0, n = 0;
  for (int e = 0; e < NSEG; e++) {
    segoff[e] = off;
    int c = counts[e];
    for (int my = 0; my * 256 < c; my++) ytab[n++] = e * 256 + my;
    off += c;
  }
  *nyt = n;
}

// -------- gather: Xg[segoff[e]+r] = Xb[lists[e][r]] (contiguous A for gemm1) --------
__global__ __launch_bounds__(256) void gather_kernel(
    const u16* __restrict__ xb, const int* __restrict__ lists,
    const int* __restrict__ counts, const int* __restrict__ segoff,
    u16* __restrict__ xg)
{
  int e = blockIdx.y;
  int cnt = counts[e], seg = segoff[e];
  const int* list = lists + e * T_TOK;
  int tid = threadIdx.x;
  for (int r = blockIdx.x; r < cnt; r += gridDim.x) {
    int tok = list[r];
    *(u16x4*)(xg + (size_t)(seg + r) * DDIM + tid * 4) =
        *(const u16x4*)(xb + (size_t)tok * DDIM + tid * 4);
  }
}

// ------------- transpose + fp32->bf16 cast: [z][R][C] -> [z][C][R] -------------
__global__ __launch_bounds__(256) void transpose_bf16_kernel(
    const float* __restrict__ rin, const float* __restrict__ sin_,
    u16* __restrict__ rout, u16* __restrict__ sout, int R, int C)
{
  __shared__ float tile[32][33];
  int b = blockIdx.z;
  const float* inb = (b < NEXP) ? rin + (size_t)b * R * C : sin_;
  u16* outb = (b < NEXP) ? rout + (size_t)b * R * C : sout;
  int r0 = blockIdx.y * 32, c0 = blockIdx.x * 32;
  int tx = threadIdx.x & 31, ty = threadIdx.x >> 5;
#pragma unroll
  for (int j = 0; j < 4; j++) {
    int r = ty + j * 8;
    tile[r][tx] = inb[(size_t)(r0 + r) * C + c0 + tx];
  }
  __syncthreads();
#pragma unroll
  for (int j = 0; j < 4; j++) {
    int rr = ty + j * 8;
    outb[(size_t)(c0 + rr) * R + r0 + tx] = f2bf(tile[tx][rr]);
  }
}

// bijective XCD-chunked tile range for this block (m204 variant):
// consecutive tiles -> same XCD (blockIdx%8 heuristic) for L2 panel reuse.
__device__ __forceinline__ void xcd_range(int ntile, int& start, int& cntx,
                                          int& pos, int& stride) {
  int q = ntile >> 3, r = ntile & 7;
  int xcd = blockIdx.x & 7;
  pos = blockIdx.x >> 3;
  stride = gridDim.x >> 3;
  start = (xcd < r) ? xcd * (q + 1) : r * (q + 1) + (xcd - r) * q;
  cntx = q + ((xcd < r) ? 1 : 0);
}

// =====================================================================
// GEMM core v8 (= round-7 proven schedule): 256x256 tile, BK=32, 8 waves
// (2M x 4N; wave owns 128x64), FOUR LDS buffers (128 KB), DEPTH-2
// prefetch, counted vmcnt, one raw barrier per K-step. A is CONTIGUOUS
// (Xg / H1 segment rows) in both GEMMs now.
// =====================================================================

// ---------------- GEMM1: H1 = gelu(Xg @ W1 + b1), bf16 out ----------------
__global__ __launch_bounds__(512) void gemm1_kernel(
    const u16* __restrict__ Xg, const u16* __restrict__ rw1t,
    const u16* __restrict__ sw1t, const float* __restrict__ rb1,
    const float* __restrict__ sb1, const int* __restrict__ counts,
    const int* __restrict__ segoff, const int* __restrict__ ytab,
    const int* __restrict__ nyt, u16* __restrict__ H1)
{
  __shared__ u16 Alds[4][256 * 32];   // 16 KB x4
  __shared__ u16 Blds[4][256 * 32];   // 16 KB x4

  int tid = threadIdx.x, lane = tid & 63;
  int wv = tid >> 6, wm = wv >> 2, wn = wv & 3;
  int kc = lane >> 4, lr = lane & 15;

  int srow[2], soff[2];
#pragma unroll
  for (int j = 0; j < 2; j++) {
    int i = j * 512 + tid;
    srow[j] = i >> 2;
    soff[j] = (((i & 3) ^ swz4(i >> 2)) * 8);
  }
  int aoff[8], boff[4];
#pragma unroll
  for (int f = 0; f < 8; f++) {
    int ra = wm * 128 + f * 16 + lr;
    aoff[f] = ra * 32 + ((kc ^ swz4(ra)) * 8);
  }
#pragma unroll
  for (int f = 0; f < 4; f++) {
    int rb_ = wn * 64 + f * 16 + lr;
    boff[f] = rb_ * 32 + ((kc ^ swz4(rb_)) * 8);
  }

  int ntile = nyt[0] * (HDIM / 256);
  int start, cntx, pos, stride;
  xcd_range(ntile, start, cntx, pos, stride);
  for (int p = pos; p < cntx; p += stride) {
    int t = start + p;
    int yt = t >> 3, nx = t & 7;
    int em = ytab[yt];
    int e = em >> 8, m0 = (em & 255) * 256, n0 = nx * 256;
    int cnt = counts[e];
    const u16* Bt = (e < NEXP) ? (rw1t + (size_t)e * HDIM * DDIM) : sw1t;
    const float* bias = (e < NEXP) ? (rb1 + (size_t)e * HDIM) : sb1;
    int seg = segoff[e];

    size_t abase[2], bbase[2];
#pragma unroll
    for (int j = 0; j < 2; j++) {
      abase[j] = (size_t)(seg + min(m0 + srow[j], cnt - 1)) * DDIM + soff[j];
      bbase[j] = (size_t)(n0 + srow[j]) * DDIM + soff[j];
    }

    f32x4 acc[8][4];
#pragma unroll
    for (int i = 0; i < 8; i++)
#pragma unroll
      for (int j = 0; j < 4; j++) acc[i][j] = (f32x4){0.f, 0.f, 0.f, 0.f};

    const int NS = DDIM / 32;   // 32 steps
#pragma unroll
    for (int s = 0; s < 2; s++)
#pragma unroll
      for (int j = 0; j < 2; j++) {
        int i = j * 512 + tid;
        gload16(Xg + abase[j] + s * 32, &Alds[s][i * 8]);
        gload16(Bt + bbase[j] + s * 32, &Blds[s][i * 8]);
      }

    for (int s = 0; s < NS; s++) {
      if (s + 2 < NS) {
        int kk = (s + 2) * 32;
        int nb = (s + 2) & 3;
#pragma unroll
        for (int j = 0; j < 2; j++) {
          int i = j * 512 + tid;
          gload16(Xg + abase[j] + kk, &Alds[nb][i * 8]);
          gload16(Bt + bbase[j] + kk, &Blds[nb][i * 8]);
        }
        asm volatile("s_waitcnt vmcnt(8)" ::: "memory");
      } else if (s + 1 < NS) {
        asm volatile("s_waitcnt vmcnt(4)" ::: "memory");
      } else {
        asm volatile("s_waitcnt vmcnt(0)" ::: "memory");
      }
      __builtin_amdgcn_s_barrier();
      __builtin_amdgcn_sched_barrier(0);

      const u16* Ac = &Alds[s & 3][0];
      const u16* Bc = &Blds[s & 3][0];
      bf16x8 af[8], bfr[4];
#pragma unroll
      for (int f = 0; f < 8; f++) af[f] = *(const bf16x8*)(Ac + aoff[f]);
#pragma unroll
      for (int f = 0; f < 4; f++) bfr[f] = *(const bf16x8*)(Bc + boff[f]);
      __builtin_amdgcn_s_setprio(1);
#pragma unroll
      for (int mf = 0; mf < 8; mf++)
#pragma unroll
        for (int nf = 0; nf < 4; nf++)
          acc[mf][nf] = __builtin_amdgcn_mfma_f32_16x16x32_bf16(af[mf], bfr[nf], acc[mf][nf], 0, 0, 0);
      __builtin_amdgcn_s_setprio(0);
    }

#pragma unroll
    for (int nf = 0; nf < 4; nf++) {
      int col = n0 + wn * 64 + nf * 16 + lr;
      float b = bias[col];
#pragma unroll
      for (int mf = 0; mf < 8; mf++) {
#pragma unroll
        for (int rg = 0; rg < 4; rg++) {
          int mt = wm * 128 + mf * 16 + kc * 4 + rg;
          if (m0 + mt < cnt) {
            float v = acc[mf][nf][rg] + b;
            H1[(size_t)(seg + m0 + mt) * HDIM + col] = f2bf(gelu_exact(v));
          }
        }
      }
    }
    __builtin_amdgcn_s_barrier();
    __builtin_amdgcn_sched_barrier(0);
  }
}

// ------------- GEMM2: out[tok] += w * (H1seg @ W2 + b2), fp32 atomics -------------
__global__ __launch_bounds__(512) void gemm2_kernel(
    const u16* __restrict__ H1, const u16* __restrict__ rw2t,
    const u16* __restrict__ sw2t, const float* __restrict__ rb2,
    const float* __restrict__ sb2, const float* __restrict__ weights,
    const int* __restrict__ counts, const int* __restrict__ segoff,
    const int* __restrict__ lists, const int* __restrict__ ytab,
    const int* __restrict__ nyt, float* __restrict__ out)
{
  __shared__ u16 Alds[4][256 * 32];
  __shared__ u16 Blds[4][256 * 32];

  int tid = threadIdx.x, lane = tid & 63;
  int wv = tid >> 6, wm = wv >> 2, wn = wv & 3;
  int kc = lane >> 4, lr = lane & 15;

  int srow[2], soff[2];
#pragma unroll
  for (int j = 0; j < 2; j++) {
    int i = j * 512 + tid;
    srow[j] = i >> 2;
    soff[j] = (((i & 3) ^ swz4(i >> 2)) * 8);
  }
  int aoff[8], boff[4];
#pragma unroll
  for (int f = 0; f < 8; f++) {
    int ra = wm * 128 + f * 16 + lr;
    aoff[f] = ra * 32 + ((kc ^ swz4(ra)) * 8);
  }
#pragma unroll
  for (int f = 0; f < 4; f++) {
    int rb_ = wn * 64 + f * 16 + lr;
    boff[f] = rb_ * 32 + ((kc ^ swz4(rb_)) * 8);
  }

  int ntile = nyt[0] * (DDIM / 256) * 2;
  int start, cntx, pos, stride;
  xcd_range(ntile, start, cntx, pos, stride);
  for (int p = pos; p < cntx; p += stride) {
    int t = start + p;
    int kh = t & 1, nx = (t >> 1) & 3, yt = t >> 3;
    int em = ytab[yt];
    int e = em >> 8, m0 = (em & 255) * 256, n0 = nx * 256;
    int cnt = counts[e];
    const u16* Bt = (e < NEXP) ? (rw2t + (size_t)e * DDIM * HDIM) : sw2t;
    const float* bias = (e < NEXP) ? (rb2 + (size_t)e * DDIM) : sb2;
    const int* list = lists + e * T_TOK;
    int seg = segoff[e];
    int k0 = kh * 1024;

    size_t abase[2], bbase[2];
#pragma unroll
    for (int j = 0; j < 2; j++) {
      abase[j] = (size_t)(seg + min(m0 + srow[j], cnt - 1)) * HDIM + k0 + soff[j];
      bbase[j] = (size_t)(n0 + srow[j]) * HDIM + k0 + soff[j];
    }

    f32x4 acc[8][4];
#pragma unroll
    for (int i = 0; i < 8; i++)
#pragma unroll
      for (int j = 0; j < 4; j++) acc[i][j] = (f32x4){0.f, 0.f, 0.f, 0.f};

    const int NS = 1024 / 32;   // 32 steps
#pragma unroll
    for (int s = 0; s < 2; s++)
#pragma unroll
      for (int j = 0; j < 2; j++) {
        int i = j * 512 + tid;
        gload16(H1 + abase[j] + s * 32, &Alds[s][i * 8]);
        gload16(Bt + bbase[j] + s * 32, &Blds[s][i * 8]);
      }

    for (int s = 0; s < NS; s++) {
      if (s + 2 < NS) {
        int kk = (s + 2) * 32;
        int nb = (s + 2) & 3;
#pragma unroll
        for (int j = 0; j < 2; j++) {
          int i = j * 512 + tid;
          gload16(H1 + abase[j] + kk, &Alds[nb][i * 8]);
          gload16(Bt + bbase[j] + kk, &Blds[nb][i * 8]);
        }
        asm volatile("s_waitcnt vmcnt(8)" ::: "memory");
      } else if (s + 1 < NS) {
        asm volatile("s_waitcnt vmcnt(4)" ::: "memory");
      } else {
        asm volatile("s_waitcnt vmcnt(0)" ::: "memory");
      }
      __builtin_amdgcn_s_barrier();
      __builtin_amdgcn_sched_barrier(0);

      const u16* Ac = &Alds[s & 3][0];
      const u16* Bc = &Blds[s & 3][0];
      bf16x8 af[8], bfr[4];
#pragma unroll
      for (int f = 0; f < 8; f++) af[f] = *(const bf16x8*)(Ac + aoff[f]);
#pragma unroll
      for (int f = 0; f < 4; f++) bfr[f] = *(const bf16x8*)(Bc + boff[f]);
      __builtin_amdgcn_s_setprio(1);
#pragma unroll
      for (int mf = 0; mf < 8; mf++)
#pragma unroll
        for (int nf = 0; nf < 4; nf++)
          acc[mf][nf] = __builtin_amdgcn_mfma_f32_16x16x32_bf16(af[mf], bfr[nf], acc[mf][nf], 0, 0, 0);
      __builtin_amdgcn_s_setprio(0);
    }

    float biasv[4];
#pragma unroll
    for (int nf = 0; nf < 4; nf++)
      biasv[nf] = (kh == 0) ? bias[n0 + wn * 64 + nf * 16 + lr] : 0.f;

#pragma unroll
    for (int mf = 0; mf < 8; mf++) {
#pragma unroll
      for (int rg = 0; rg < 4; rg++) {
        int mt = wm * 128 + mf * 16 + kc * 4 + rg;
        int mrow = m0 + mt;
        if (mrow < cnt) {
          int tok = list[mrow];
          float w = (e < NEXP) ? weights[(size_t)tok * NEXP + e] : 1.0f;
          float* orow = out + (size_t)tok * DDIM + n0 + wn * 64 + lr;
#pragma unroll
          for (int nf = 0; nf < 4; nf++)
            atomicAdd(orow + nf * 16, w * (acc[mf][nf][rg] + biasv[nf]));
        }
      }
    }
    __builtin_amdgcn_s_barrier();
    __builtin_amdgcn_sched_barrier(0);
  }
}

// ---------------- launcher ----------------
extern "C" void kernel_launch(void* const* d_in, const int* in_sizes, int n_in,
                              void* d_out, int out_size, void* d_ws, size_t ws_size,
                              hipStream_t stream) {
  (void)in_sizes; (void)n_in; (void)out_size; (void)ws_size;
  const float* hidden   = (const float*)d_in[0];
  const float* router_w = (const float*)d_in[1];
  const float* router_b = (const float*)d_in[2];
  const float* sw1 = (const float*)d_in[3];
  const float* sb1 = (const float*)d_in[4];
  const float* sw2 = (const float*)d_in[5];
  const float* sb2 = (const float*)d_in[6];
  const float* rw1 = (const float*)d_in[7];
  const float* rb1 = (const float*)d_in[8];
  const float* rw2 = (const float*)d_in[9];
  const float* rb2 = (const float*)d_in[10];
  float* out = (float*)d_out;

  char* ws = (char*)d_ws;
  u16* Xb      = (u16*)(ws + 0);            //  4,194,304  [T][D] bf16
  u16* rw1t    = (u16*)(ws + 4194304);      // 33,554,432  [E][H][D] bf16 (B^T)
  u16* rw2t    = (u16*)(ws + 37748736);     // 33,554,432  [E][D][H] bf16 (B^T)
  u16* Xg      = (u16*)(ws + 37748736);     // 12,582,912  [6144][D] -- ALIASES
                                            // rw2t: dead before transposeW2
  u16* sw1t    = (u16*)(ws + 71303168);     //  4,194,304  [H][D]
  u16* sw2t    = (u16*)(ws + 75497472);     //  4,194,304  [D][H]
  u16* H1      = (u16*)(ws + 79691776);     // 25,165,824  [6144][H] bf16
  float* weights = (float*)(ws + 104857600);//     65,536  [T][E]
  int* counts  = (int*)(ws + 104923136);    //         64
  int* segoff  = (int*)(ws + 104923200);    //         64
  int* lists   = (int*)(ws + 104923264);    //     73,728  [NSEG][T]
  int* ytab    = (int*)(ws + 104996992);    //        640
  int* nyt     = (int*)(ws + 104997632);    //          4

  hipMemsetAsync(counts, 0, 64, stream);
  hipMemsetAsync(out, 0, (size_t)T_TOK * DDIM * sizeof(float), stream);

  router_kernel<<<T_TOK / 4, 256, 0, stream>>>(hidden, router_w, router_b, Xb,
                                               weights, counts, lists);
  seg_kernel<<<1, 1, 0, stream>>>(counts, segoff, ytab, nyt);

  // W1 transpose first; W2 transpose AFTER gemm1 (Xg aliases rw2t space)
  transpose_bf16_kernel<<<dim3(HDIM / 32, DDIM / 32, NSEG), 256, 0, stream>>>(
      rw1, sw1, rw1t, sw1t, DDIM, HDIM);

  gather_kernel<<<dim3(64, NSEG), 256, 0, stream>>>(Xb, lists, counts, segoff, Xg);

  gemm1_kernel<<<256, 512, 0, stream>>>(
      Xg, rw1t, sw1t, rb1, sb1, counts, segoff, ytab, nyt, H1);

  transpose_bf16_kernel<<<dim3(DDIM / 32, HDIM / 32, NSEG), 256, 0, stream>>>(
      rw2, sw2, rw2t, sw2t, HDIM, DDIM);

  gemm2_kernel<<<256, 512, 0, stream>>>(
      H1, rw2t, sw2t, rb2, sb2, weights, counts, segoff, lists, ytab, nyt, out);
}

// Round 9
// 229.277 us; speedup vs baseline: 1.2085x; 1.2085x over previous
//
#include <hip/hip_runtime.h>
#include <hip/hip_bf16.h>

#define T_TOK 2048
#define DDIM  1024
#define HDIM  2048
#define NEXP  8
#define NSEG  9   // 8 routed + 1 shared

typedef unsigned short u16;
typedef __attribute__((ext_vector_type(4))) float f32x4;
typedef __attribute__((ext_vector_type(8))) short bf16x8;
typedef __attribute__((ext_vector_type(4))) unsigned short u16x4;

__device__ __forceinline__ u16 f2bf(float x) {
  union { float f; unsigned int u; } v; v.f = x;
  unsigned int r = v.u + 0x7fffu + ((v.u >> 16) & 1u);
  return (u16)(r >> 16);
}
__device__ __forceinline__ float gelu_exact(float x) {
  return 0.5f * x * (1.0f + erff(x * 0.70710678118654752f));
}
// chunk swizzle for 64B rows (4 x 16B chunks)
__device__ __forceinline__ int swz4(int row) {
  return (row & 3) ^ ((row >> 2) & 3);
}

__device__ __forceinline__ void gload16(const void* g, void* l) {
  __builtin_amdgcn_global_load_lds(
      (const __attribute__((address_space(1))) unsigned int*)g,
      (__attribute__((address_space(3))) unsigned int*)l, 16, 0, 0);
}

// ---------------- router: logits, softmax, top-2, lists, bf16 X ----------------
__global__ __launch_bounds__(256) void router_kernel(
    const float* __restrict__ x, const float* __restrict__ rw,
    const float* __restrict__ rb, u16* __restrict__ xb,
    float* __restrict__ weights, int* __restrict__ counts,
    int* __restrict__ lists)
{
  int wv = threadIdx.x >> 6, lane = threadIdx.x & 63;
  int t = blockIdx.x * 4 + wv;            // one wave per token
  const float* xrow = x + (size_t)t * DDIM;
  float acc[NEXP];
#pragma unroll
  for (int e = 0; e < NEXP; e++) acc[e] = 0.f;
#pragma unroll
  for (int i = 0; i < 4; i++) {
    int d0 = i * 256 + lane * 4;
    f32x4 xv = *(const f32x4*)(xrow + d0);
    u16x4 pk;
#pragma unroll
    for (int j = 0; j < 4; j++) {
      float xs = xv[j];
      pk[j] = f2bf(xs);
      const float* wr = rw + (size_t)(d0 + j) * NEXP;
#pragma unroll
      for (int e = 0; e < NEXP; e++) acc[e] = fmaf(xs, wr[e], acc[e]);
    }
    *(u16x4*)(xb + (size_t)t * DDIM + d0) = pk;
  }
#pragma unroll
  for (int off = 32; off >= 1; off >>= 1)
#pragma unroll
    for (int e = 0; e < NEXP; e++) acc[e] += __shfl_xor(acc[e], off);

  if (lane == 0) {
    float lg[NEXP], mx = -1e30f;
#pragma unroll
    for (int e = 0; e < NEXP; e++) { lg[e] = acc[e] + rb[e]; mx = fmaxf(mx, lg[e]); }
    float p[NEXP], s = 0.f;
#pragma unroll
    for (int e = 0; e < NEXP; e++) { p[e] = expf(lg[e] - mx); s += p[e]; }
    float inv = 1.0f / s;
#pragma unroll
    for (int e = 0; e < NEXP; e++) p[e] *= inv;
    int i1 = 0;
#pragma unroll
    for (int e = 1; e < NEXP; e++) if (p[e] > p[i1]) i1 = e;
    int i2 = (i1 == 0) ? 1 : 0;
#pragma unroll
    for (int e = 0; e < NEXP; e++) if (e != i1 && p[e] > p[i2]) i2 = e;
#pragma unroll
    for (int e = 0; e < NEXP; e++)
      weights[(size_t)t * NEXP + e] = (e == i1) ? p[i1] : (e == i2) ? p[i2] : 0.f;
    int p1 = atomicAdd(counts + i1, 1); lists[i1 * T_TOK + p1] = t;
    int p2 = atomicAdd(counts + i2, 1); lists[i2 * T_TOK + p2] = t;
    lists[NEXP * T_TOK + t] = t;        // shared segment: identity
  }
}

// seg offsets + compact y-tile table (e*256+my for non-empty 256-row tiles)
__global__ void seg_kernel(int* counts, int* segoff, int* ytab, int* nyt) {
  counts[NEXP] = T_TOK;
  int off = 0, n = 0;
  for (int e = 0; e < NSEG; e++) {
    segoff[e] = off;
    int c = counts[e];
    for (int my = 0; my * 256 < c; my++) ytab[n++] = e * 256 + my;
    off += c;
  }
  *nyt = n;
}

// =====================================================================
// GEMM core v9: round-7 proven sync skeleton (256x256 tile, BK=32,
// 8 waves 2Mx4N, one raw barrier per K-step, counted vmcnt) with the
// fp32->bf16 WEIGHT TRANSPOSE FUSED into B-staging:
//   A: gload_lds, 4 buffers, depth-2 prefetch (as round 7, proven).
//   B: wave wv loads W[k0+wv*4 .. +3][n0 + lane*4 ..+3] fp32 (coalesced,
//      natural [K][N] layout, issued 1 step ahead into regs), cvt->bf16,
//      ds_write_b64 into swizzled B-LDS (slot = chunk ^ swz4(row), the
//      exact inverse of the proven read path). 2 buffers: write in
//      window (s-1,s), read in window (s,s+1), separated by barrier(s).
//   lgkmcnt(0) drains ds_writes before each barrier.
// vmcnt: steady outstanding after issues = B(s+1)x4 + A(s+2)x2 + A(s+1)x2
//   -> vmcnt(8) waits A(s); tail: 6 then 0. (B(s) regs are drained by the
//   compiler's own wait at the cvt, so they never count here.)
// =====================================================================

// ---------------- GEMM1: H1 = gelu(gather(Xb) @ W1 + b1), bf16 out ----------------
__global__ __launch_bounds__(512) void gemm1_kernel(
    const u16* __restrict__ Xb, const float* __restrict__ rw1,
    const float* __restrict__ sw1, const float* __restrict__ rb1,
    const float* __restrict__ sb1, const int* __restrict__ counts,
    const int* __restrict__ segoff, const int* __restrict__ lists,
    const int* __restrict__ ytab, const int* __restrict__ nyt,
    u16* __restrict__ H1)
{
  __shared__ u16 Alds[4][256 * 32];   // 16 KB x4
  __shared__ u16 Blds[2][256 * 32];   // 16 KB x2  (96 KB total)

  int tid = threadIdx.x, lane = tid & 63;
  int wv = tid >> 6, wm = wv >> 2, wn = wv & 3;
  int kc = lane >> 4, lr = lane & 15;

  // A staging: chunk i = j*512+tid; row=i>>2, linear LDS dest, swizzled src
  int srow[2], soff[2];
#pragma unroll
  for (int j = 0; j < 2; j++) {
    int i = j * 512 + tid;
    srow[j] = i >> 2;
    soff[j] = (((i & 3) ^ swz4(i >> 2)) * 8);
  }
  // fragment read offsets (elems): row r, chunk kc ^ swz4(r)
  int aoff[8], boff[4];
#pragma unroll
  for (int f = 0; f < 8; f++) {
    int ra = wm * 128 + f * 16 + lr;
    aoff[f] = ra * 32 + ((kc ^ swz4(ra)) * 8);
  }
#pragma unroll
  for (int f = 0; f < 4; f++) {
    int rb_ = wn * 64 + f * 16 + lr;
    boff[f] = rb_ * 32 + ((kc ^ swz4(rb_)) * 8);
  }
  // B ds_write offsets (elems) for rows n = lane*4+j, k-base = wv*4:
  // slot = (wv>>1) ^ swz4(n); swz4(lane*4+j) = j ^ (lane&3)
  int bw[4];
#pragma unroll
  for (int j = 0; j < 4; j++)
    bw[j] = ((lane << 2) + j) * 32 + (((wv >> 1) ^ j ^ (lane & 3)) << 3) + ((wv & 1) << 2);

  int ntile = nyt[0] * (HDIM / 256);
  for (int t = blockIdx.x; t < ntile; t += gridDim.x) {
    int yt = t >> 3, nx = t & 7;
    int em = ytab[yt];
    int e = em >> 8, m0 = (em & 255) * 256, n0 = nx * 256;
    int cnt = counts[e];
    const float* Wf = (e < NEXP) ? (rw1 + (size_t)e * DDIM * HDIM) : sw1;
    const float* bias = (e < NEXP) ? (rb1 + (size_t)e * HDIM) : sb1;
    const int* list = lists + e * T_TOK;
    int seg = segoff[e];

    size_t abase[2];
#pragma unroll
    for (int j = 0; j < 2; j++) {
      int tok = list[min(m0 + srow[j], cnt - 1)];
      abase[j] = (size_t)tok * DDIM + soff[j];
    }
    const float* Wb = Wf + n0 + (lane << 2);   // + k*HDIM per row

    f32x4 acc[8][4];
#pragma unroll
    for (int i = 0; i < 8; i++)
#pragma unroll
      for (int j = 0; j < 4; j++) acc[i][j] = (f32x4){0.f, 0.f, 0.f, 0.f};

    const int NS = DDIM / 32;   // 32 steps
    // prologue: B(0) regs; A(0)->buf0, A(1)->buf1
    f32x4 vBa, vBb, vBc, vBd;
    {
      const float* Wk = Wb + (size_t)(wv * 4) * HDIM;
      vBa = *(const f32x4*)(Wk);
      vBb = *(const f32x4*)(Wk + HDIM);
      vBc = *(const f32x4*)(Wk + 2 * HDIM);
      vBd = *(const f32x4*)(Wk + 3 * HDIM);
    }
#pragma unroll
    for (int s = 0; s < 2; s++)
#pragma unroll
      for (int j = 0; j < 2; j++) {
        int i = j * 512 + tid;
        gload16(Xb + abase[j] + s * 32, &Alds[s][i * 8]);
      }

    for (int s = 0; s < NS; s++) {
      // A prefetch depth-2
      if (s + 2 < NS) {
        int kk = (s + 2) * 32;
        int nb = (s + 2) & 3;
#pragma unroll
        for (int j = 0; j < 2; j++) {
          int i = j * 512 + tid;
          gload16(Xb + abase[j] + kk, &Alds[nb][i * 8]);
        }
      }
      // cvt B(s) regs -> bf16 -> LDS (compiler inserts the vmcnt for vB*)
      {
        u16* Bd = &Blds[s & 1][0];
#pragma unroll
        for (int j = 0; j < 4; j++) {
          u16x4 pk;
          pk[0] = f2bf(vBa[j]); pk[1] = f2bf(vBb[j]);
          pk[2] = f2bf(vBc[j]); pk[3] = f2bf(vBd[j]);
          *(u16x4*)(Bd + bw[j]) = pk;
        }
      }
      // issue B(s+1) into the (now-consumed) regs
      if (s + 1 < NS) {
        const float* Wk = Wb + (size_t)((s + 1) * 32 + wv * 4) * HDIM;
        vBa = *(const f32x4*)(Wk);
        vBb = *(const f32x4*)(Wk + HDIM);
        vBc = *(const f32x4*)(Wk + 2 * HDIM);
        vBd = *(const f32x4*)(Wk + 3 * HDIM);
      }
      if (s + 2 < NS)      asm volatile("s_waitcnt vmcnt(8)" ::: "memory");
      else if (s + 1 < NS) asm volatile("s_waitcnt vmcnt(6)" ::: "memory");
      else                 asm volatile("s_waitcnt vmcnt(0)" ::: "memory");
      asm volatile("s_waitcnt lgkmcnt(0)" ::: "memory");
      __builtin_amdgcn_s_barrier();
      __builtin_amdgcn_sched_barrier(0);

      const u16* Ac = &Alds[s & 3][0];
      const u16* Bc = &Blds[s & 1][0];
      bf16x8 af[8], bfr[4];
#pragma unroll
      for (int f = 0; f < 8; f++) af[f] = *(const bf16x8*)(Ac + aoff[f]);
#pragma unroll
      for (int f = 0; f < 4; f++) bfr[f] = *(const bf16x8*)(Bc + boff[f]);
      __builtin_amdgcn_s_setprio(1);
#pragma unroll
      for (int mf = 0; mf < 8; mf++)
#pragma unroll
        for (int nf = 0; nf < 4; nf++)
          acc[mf][nf] = __builtin_amdgcn_mfma_f32_16x16x32_bf16(af[mf], bfr[nf], acc[mf][nf], 0, 0, 0);
      __builtin_amdgcn_s_setprio(0);
    }

#pragma unroll
    for (int nf = 0; nf < 4; nf++) {
      int col = n0 + wn * 64 + nf * 16 + lr;
      float b = bias[col];
#pragma unroll
      for (int mf = 0; mf < 8; mf++) {
#pragma unroll
        for (int rg = 0; rg < 4; rg++) {
          int mt = wm * 128 + mf * 16 + kc * 4 + rg;
          if (m0 + mt < cnt) {
            float v = acc[mf][nf][rg] + b;
            H1[(size_t)(seg + m0 + mt) * HDIM + col] = f2bf(gelu_exact(v));
          }
        }
      }
    }
    __builtin_amdgcn_s_barrier();
    __builtin_amdgcn_sched_barrier(0);
  }
}

// ------------- GEMM2: out[tok] += w * (H1seg @ W2 + b2), fp32 atomics -------------
// K split in 2 halves of 1024 (bias added by half 0 only).
__global__ __launch_bounds__(512) void gemm2_kernel(
    const u16* __restrict__ H1, const float* __restrict__ rw2,
    const float* __restrict__ sw2, const float* __restrict__ rb2,
    const float* __restrict__ sb2, const float* __restrict__ weights,
    const int* __restrict__ counts, const int* __restrict__ segoff,
    const int* __restrict__ lists, const int* __restrict__ ytab,
    const int* __restrict__ nyt, float* __restrict__ out)
{
  __shared__ u16 Alds[4][256 * 32];
  __shared__ u16 Blds[2][256 * 32];

  int tid = threadIdx.x, lane = tid & 63;
  int wv = tid >> 6, wm = wv >> 2, wn = wv & 3;
  int kc = lane >> 4, lr = lane & 15;

  int srow[2], soff[2];
#pragma unroll
  for (int j = 0; j < 2; j++) {
    int i = j * 512 + tid;
    srow[j] = i >> 2;
    soff[j] = (((i & 3) ^ swz4(i >> 2)) * 8);
  }
  int aoff[8], boff[4];
#pragma unroll
  for (int f = 0; f < 8; f++) {
    int ra = wm * 128 + f * 16 + lr;
    aoff[f] = ra * 32 + ((kc ^ swz4(ra)) * 8);
  }
#pragma unroll
  for (int f = 0; f < 4; f++) {
    int rb_ = wn * 64 + f * 16 + lr;
    boff[f] = rb_ * 32 + ((kc ^ swz4(rb_)) * 8);
  }
  int bw[4];
#pragma unroll
  for (int j = 0; j < 4; j++)
    bw[j] = ((lane << 2) + j) * 32 + (((wv >> 1) ^ j ^ (lane & 3)) << 3) + ((wv & 1) << 2);

  int ntile = nyt[0] * (DDIM / 256) * 2;
  for (int t = blockIdx.x; t < ntile; t += gridDim.x) {
    int kh = t & 1, nx = (t >> 1) & 3, yt = t >> 3;
    int em = ytab[yt];
    int e = em >> 8, m0 = (em & 255) * 256, n0 = nx * 256;
    int cnt = counts[e];
    const float* Wf = (e < NEXP) ? (rw2 + (size_t)e * HDIM * DDIM) : sw2;
    const float* bias = (e < NEXP) ? (rb2 + (size_t)e * DDIM) : sb2;
    const int* list = lists + e * T_TOK;
    int seg = segoff[e];
    int k0 = kh * 1024;

    size_t abase[2];
#pragma unroll
    for (int j = 0; j < 2; j++)
      abase[j] = (size_t)(seg + min(m0 + srow[j], cnt - 1)) * HDIM + k0 + soff[j];
    const float* Wb = Wf + (size_t)k0 * DDIM + n0 + (lane << 2);

    f32x4 acc[8][4];
#pragma unroll
    for (int i = 0; i < 8; i++)
#pragma unroll
      for (int j = 0; j < 4; j++) acc[i][j] = (f32x4){0.f, 0.f, 0.f, 0.f};

    const int NS = 1024 / 32;   // 32 steps
    f32x4 vBa, vBb, vBc, vBd;
    {
      const float* Wk = Wb + (size_t)(wv * 4) * DDIM;
      vBa = *(const f32x4*)(Wk);
      vBb = *(const f32x4*)(Wk + DDIM);
      vBc = *(const f32x4*)(Wk + 2 * DDIM);
      vBd = *(const f32x4*)(Wk + 3 * DDIM);
    }
#pragma unroll
    for (int s = 0; s < 2; s++)
#pragma unroll
      for (int j = 0; j < 2; j++) {
        int i = j * 512 + tid;
        gload16(H1 + abase[j] + s * 32, &Alds[s][i * 8]);
      }

    for (int s = 0; s < NS; s++) {
      if (s + 2 < NS) {
        int kk = (s + 2) * 32;
        int nb = (s + 2) & 3;
#pragma unroll
        for (int j = 0; j < 2; j++) {
          int i = j * 512 + tid;
          gload16(H1 + abase[j] + kk, &Alds[nb][i * 8]);
        }
      }
      {
        u16* Bd = &Blds[s & 1][0];
#pragma unroll
        for (int j = 0; j < 4; j++) {
          u16x4 pk;
          pk[0] = f2bf(vBa[j]); pk[1] = f2bf(vBb[j]);
          pk[2] = f2bf(vBc[j]); pk[3] = f2bf(vBd[j]);
          *(u16x4*)(Bd + bw[j]) = pk;
        }
      }
      if (s + 1 < NS) {
        const float* Wk = Wb + (size_t)((s + 1) * 32 + wv * 4) * DDIM;
        vBa = *(const f32x4*)(Wk);
        vBb = *(const f32x4*)(Wk + DDIM);
        vBc = *(const f32x4*)(Wk + 2 * DDIM);
        vBd = *(const f32x4*)(Wk + 3 * DDIM);
      }
      if (s + 2 < NS)      asm volatile("s_waitcnt vmcnt(8)" ::: "memory");
      else if (s + 1 < NS) asm volatile("s_waitcnt vmcnt(6)" ::: "memory");
      else                 asm volatile("s_waitcnt vmcnt(0)" ::: "memory");
      asm volatile("s_waitcnt lgkmcnt(0)" ::: "memory");
      __builtin_amdgcn_s_barrier();
      __builtin_amdgcn_sched_barrier(0);

      const u16* Ac = &Alds[s & 3][0];
      const u16* Bc = &Blds[s & 1][0];
      bf16x8 af[8], bfr[4];
#pragma unroll
      for (int f = 0; f < 8; f++) af[f] = *(const bf16x8*)(Ac + aoff[f]);
#pragma unroll
      for (int f = 0; f < 4; f++) bfr[f] = *(const bf16x8*)(Bc + boff[f]);
      __builtin_amdgcn_s_setprio(1);
#pragma unroll
      for (int mf = 0; mf < 8; mf++)
#pragma unroll
        for (int nf = 0; nf < 4; nf++)
          acc[mf][nf] = __builtin_amdgcn_mfma_f32_16x16x32_bf16(af[mf], bfr[nf], acc[mf][nf], 0, 0, 0);
      __builtin_amdgcn_s_setprio(0);
    }

    float biasv[4];
#pragma unroll
    for (int nf = 0; nf < 4; nf++)
      biasv[nf] = (kh == 0) ? bias[n0 + wn * 64 + nf * 16 + lr] : 0.f;

#pragma unroll
    for (int mf = 0; mf < 8; mf++) {
#pragma unroll
      for (int rg = 0; rg < 4; rg++) {
        int mt = wm * 128 + mf * 16 + kc * 4 + rg;
        int mrow = m0 + mt;
        if (mrow < cnt) {
          int tok = list[mrow];
          float w = (e < NEXP) ? weights[(size_t)tok * NEXP + e] : 1.0f;
          float* orow = out + (size_t)tok * DDIM + n0 + wn * 64 + lr;
#pragma unroll
          for (int nf = 0; nf < 4; nf++)
            atomicAdd(orow + nf * 16, w * (acc[mf][nf][rg] + biasv[nf]));
        }
      }
    }
    __builtin_amdgcn_s_barrier();
    __builtin_amdgcn_sched_barrier(0);
  }
}

// ---------------- launcher ----------------
extern "C" void kernel_launch(void* const* d_in, const int* in_sizes, int n_in,
                              void* d_out, int out_size, void* d_ws, size_t ws_size,
                              hipStream_t stream) {
  (void)in_sizes; (void)n_in; (void)out_size; (void)ws_size;
  const float* hidden   = (const float*)d_in[0];
  const float* router_w = (const float*)d_in[1];
  const float* router_b = (const float*)d_in[2];
  const float* sw1 = (const float*)d_in[3];
  const float* sb1 = (const float*)d_in[4];
  const float* sw2 = (const float*)d_in[5];
  const float* sb2 = (const float*)d_in[6];
  const float* rw1 = (const float*)d_in[7];
  const float* rb1 = (const float*)d_in[8];
  const float* rw2 = (const float*)d_in[9];
  const float* rb2 = (const float*)d_in[10];
  float* out = (float*)d_out;

  char* ws = (char*)d_ws;
  u16* Xb      = (u16*)(ws + 0);            //  4,194,304  [T][D] bf16
  u16* H1      = (u16*)(ws + 4194304);      // 25,165,824  [6144][H] bf16
  float* weights = (float*)(ws + 29360128); //     65,536  [T][E]
  int* counts  = (int*)(ws + 29425664);     //         64
  int* segoff  = (int*)(ws + 29425728);     //         64
  int* lists   = (int*)(ws + 29425792);     //     73,728  [NSEG][T]
  int* ytab    = (int*)(ws + 29499520);     //        640
  int* nyt     = (int*)(ws + 29500160);     //          4

  hipMemsetAsync(counts, 0, 64, stream);
  hipMemsetAsync(out, 0, (size_t)T_TOK * DDIM * sizeof(float), stream);

  router_kernel<<<T_TOK / 4, 256, 0, stream>>>(hidden, router_w, router_b, Xb,
                                               weights, counts, lists);
  seg_kernel<<<1, 1, 0, stream>>>(counts, segoff, ytab, nyt);

  gemm1_kernel<<<256, 512, 0, stream>>>(
      Xb, rw1, sw1, rb1, sb1, counts, segoff, lists, ytab, nyt, H1);
  gemm2_kernel<<<256, 512, 0, stream>>>(
      H1, rw2, sw2, rb2, sb2, weights, counts, segoff, lists, ytab, nyt, out);
}